// Round 1
// baseline (132.770 us; speedup 1.0000x reference)
//
#include <hip/hip_runtime.h>
#include <stdint.h>

// SupConLossWithPrototype on MI355X.
// Round 12: exploit S-symmetry. k_main replaced by k_sym over supra-diagonal
// 128x128 tiles (2080 blocks instead of full 8192x8192 coverage): halves MFMA
// (1.05M -> 532K) and exp2 (67M -> 34M) work. B-operand is now UNMASKED
// Fc = bf16(C*f); novelty applied per element as 0/1-float FMAs on both the
// row direction (mask = novel_col) and the column direction (mask =
// novel_row). Tile (a,b) a<=b writes row-sums of group a at slot b and
// col-sums of group b at slot a (skipped when a==b) -> each of the 64 slots
// per row written exactly once: atomic-free, deterministic. k_final gathers
// 64 partials per row (float4 x 16 lanes); the (M-Nn) base-column correction
// is gone (masking is exact now). g/Nn one-time reduction moved to the first
// 8 diagonal tiles.

#define M_TOT 8192
#define K_DIM 128
#define B_PRO 100
#define INV_T 5.0f                          // 1/TEMP
#define C_SCALE 7.2134752044448170f         // 5 * log2(e)
#define INV_C   0.1386294361119891f         // ln2/5
#define RT    128                           // k_sym tile side
#define NT    (M_TOT / RT)                  // 64 row/col groups
#define NTILE (NT * (NT + 1) / 2)           // 2080 supra-diagonal tiles
#define NSLOT NT                            // partial slots per row
#define PS    136                           // k_proto2 proto LDS stride
#define FS    136                           // k_proto2 feat LDS stride

#if __has_builtin(__builtin_amdgcn_exp2f)
#define EXP2(x) __builtin_amdgcn_exp2f(x)
#else
#define EXP2(x) __expf((x) * 0.6931471805599453f)
#endif

typedef __attribute__((ext_vector_type(8))) short  short8;   // 8 bf16 (MFMA A/B frag)
typedef __attribute__((ext_vector_type(4))) float  floatx4;  // MFMA C/D frag

__device__ __forceinline__ float bf2f(unsigned short u) {
    union { unsigned int i; float f; } v; v.i = ((unsigned int)u) << 16; return v.f;
}
__device__ __forceinline__ unsigned short f2bf(float x) {   // RNE
    union { float f; unsigned int i; } v; v.f = x;
    return (unsigned short)((v.i + 0x7fffu + ((v.i >> 16) & 1u)) >> 16);
}
__device__ __forceinline__ float lo_bf(unsigned int u) {
    union { unsigned int i; float f; } v; v.i = u << 16; return v.f;
}
__device__ __forceinline__ float hi_bf(unsigned int u) {
    union { unsigned int i; float f; } v; v.i = u & 0xffff0000u; return v.f;
}

// ---------------------------------------------------------------- k_proto2
// 512 blocks x 256 thr; 16 feature rows per block. Emits Psum/expPsum/PLab/nf,
// Fb = bf16(f), Fc = bf16(C*f) UNMASKED, gpart[block] = block colsum of the
// novel-masked Fc values (bit-identical to the old Fz colsum), nfcnt[block]
// = block novel count. Block 0 zeroes out[0].
__global__ __launch_bounds__(256) void k_proto2(
        const float* __restrict__ feat, const int* __restrict__ labels,
        const float* __restrict__ protos, const int* __restrict__ plabels,
        float* __restrict__ Psum, float* __restrict__ expPsum,
        float* __restrict__ PLab, int* __restrict__ nf,
        int* __restrict__ nfcnt,
        unsigned short* __restrict__ Fb, unsigned short* __restrict__ Fc,
        float* __restrict__ gpart, float* __restrict__ out) {
    __shared__ unsigned short protoB[128 * PS];
    __shared__ unsigned short featB[16 * FS];
    __shared__ float zcol[16][128];
    __shared__ int labL[16];
    __shared__ int plabL[B_PRO];
    __shared__ int novL[16];

    const int tid = threadIdx.x;
    const int rowBase = blockIdx.x * 16;

    if (blockIdx.x == 0 && tid == 0) out[0] = 0.f;   // k_final accumulates later

    if (tid < B_PRO) plabL[tid] = plabels[tid];
    if (tid >= 128 && tid < 144) labL[tid - 128] = labels[rowBase + tid - 128];

    // stage protos -> bf16 LDS (rows >= 100 zeroed). thread: row tid>>1, half tid&1.
    {
        const int pr = tid >> 1, h = tid & 1;
        unsigned short* dst = &protoB[pr * PS + h * 64];
        if (pr < B_PRO) {
            const float* src = protos + pr * K_DIM + h * 64;
            #pragma unroll
            for (int j = 0; j < 16; ++j) {
                float4 v = ((const float4*)src)[j];
                *(ushort4*)&dst[j * 4] = make_ushort4(f2bf(v.x), f2bf(v.y), f2bf(v.z), f2bf(v.w));
            }
        } else {
            #pragma unroll
            for (int j = 0; j < 16; ++j) *(ushort4*)&dst[j * 4] = make_ushort4(0, 0, 0, 0);
        }
    }

    // stage this thread's feat segment (row rp, cols pq*8..+7) -> LDS + Fb.
    const int rp = tid >> 4, pq = tid & 15;
    float4 fa, fb4;
    {
        const float* src = feat + (size_t)(rowBase + rp) * K_DIM + pq * 8;
        fa  = ((const float4*)src)[0];
        fb4 = ((const float4*)src)[1];
        ushort4 o0 = make_ushort4(f2bf(fa.x), f2bf(fa.y), f2bf(fa.z), f2bf(fa.w));
        ushort4 o1 = make_ushort4(f2bf(fb4.x), f2bf(fb4.y), f2bf(fb4.z), f2bf(fb4.w));
        *(ushort4*)&featB[rp * FS + pq * 8]     = o0;
        *(ushort4*)&featB[rp * FS + pq * 8 + 4] = o1;
        unsigned short* fbd = Fb + (size_t)(rowBase + rp) * K_DIM + pq * 8;
        *(ushort4*)&fbd[0] = o0;
        *(ushort4*)&fbd[4] = o1;
    }
    __syncthreads();

    float acc[8];
    #pragma unroll
    for (int s = 0; s < 8; ++s) acc[s] = 0.f;

    const unsigned short* fRow = &featB[rp * FS];
    for (int kc = 0; kc < K_DIM; kc += 16) {
        uint4 q0 = *(const uint4*)&fRow[kc];
        uint4 q1 = *(const uint4*)&fRow[kc + 8];
        float f[16];
        f[0]=lo_bf(q0.x); f[1]=hi_bf(q0.x); f[2]=lo_bf(q0.y); f[3]=hi_bf(q0.y);
        f[4]=lo_bf(q0.z); f[5]=hi_bf(q0.z); f[6]=lo_bf(q0.w); f[7]=hi_bf(q0.w);
        f[8]=lo_bf(q1.x); f[9]=hi_bf(q1.x); f[10]=lo_bf(q1.y); f[11]=hi_bf(q1.y);
        f[12]=lo_bf(q1.z); f[13]=hi_bf(q1.z); f[14]=lo_bf(q1.w); f[15]=hi_bf(q1.w);
        #pragma unroll
        for (int s = 0; s < 8; ++s) {
            const int b = pq + (s & 3) * 16 + (s >> 2) * 64;
            const unsigned short* pRow = &protoB[b * PS];
            uint4 p0 = *(const uint4*)&pRow[kc];
            uint4 p1 = *(const uint4*)&pRow[kc + 8];
            float a = acc[s];
            a += lo_bf(p0.x)*f[0];  a += hi_bf(p0.x)*f[1];
            a += lo_bf(p0.y)*f[2];  a += hi_bf(p0.y)*f[3];
            a += lo_bf(p0.z)*f[4];  a += hi_bf(p0.z)*f[5];
            a += lo_bf(p0.w)*f[6];  a += hi_bf(p0.w)*f[7];
            a += lo_bf(p1.x)*f[8];  a += hi_bf(p1.x)*f[9];
            a += lo_bf(p1.y)*f[10]; a += hi_bf(p1.y)*f[11];
            a += lo_bf(p1.z)*f[12]; a += hi_bf(p1.z)*f[13];
            a += lo_bf(p1.w)*f[14]; a += hi_bf(p1.w)*f[15];
            acc[s] = a;
        }
    }

    // per-row epilogue: mask b<100, reduce over the 16 pq lanes
    const int lbl = labL[rp];
    float psum = 0.f, esum = 0.f, plab = 0.f, flg = 0.f;
    #pragma unroll
    for (int s = 0; s < 8; ++s) {
        const int b = pq + (s & 3) * 16 + (s >> 2) * 64;
        if (b < B_PRO) {
            const float Pv = acc[s] * INV_T;
            psum += Pv;
            esum += __expf(Pv);
            if (b == lbl) plab += Pv;
            if (plabL[b] == lbl) flg = 1.f;
        }
    }
    for (int off = 1; off < 16; off <<= 1) {
        psum += __shfl_xor(psum, off);
        esum += __shfl_xor(esum, off);
        plab += __shfl_xor(plab, off);
        flg  += __shfl_xor(flg,  off);
    }

    // Fc write (ALWAYS scaled, unmasked) + zcol (novel-masked exact bf16 values)
    {
        const bool nov = (flg == 0.f);
        ushort4 s0 = make_ushort4(f2bf(fa.x*C_SCALE), f2bf(fa.y*C_SCALE),
                                  f2bf(fa.z*C_SCALE), f2bf(fa.w*C_SCALE));
        ushort4 s1 = make_ushort4(f2bf(fb4.x*C_SCALE), f2bf(fb4.y*C_SCALE),
                                  f2bf(fb4.z*C_SCALE), f2bf(fb4.w*C_SCALE));
        unsigned short* fcd = Fc + (size_t)(rowBase + rp) * K_DIM + pq * 8;
        *(ushort4*)&fcd[0] = s0;
        *(ushort4*)&fcd[4] = s1;
        const float m = nov ? 1.f : 0.f;
        float* zc = &zcol[rp][pq * 8];
        zc[0] = m*bf2f(s0.x); zc[1] = m*bf2f(s0.y); zc[2] = m*bf2f(s0.z); zc[3] = m*bf2f(s0.w);
        zc[4] = m*bf2f(s1.x); zc[5] = m*bf2f(s1.y); zc[6] = m*bf2f(s1.z); zc[7] = m*bf2f(s1.w);

        if (pq == 0) {
            const int i = rowBase + rp;
            Psum[i] = psum; expPsum[i] = esum; PLab[i] = plab;
            const int nv = nov ? 1 : 0;
            nf[i] = nv;
            novL[rp] = nv;
        }
    }

    __syncthreads();
    if (tid < 128) {
        float s = 0.f;
        #pragma unroll
        for (int r = 0; r < 16; ++r) s += zcol[r][tid];
        gpart[blockIdx.x * 128 + tid] = s;         // non-atomic partial
    } else if (tid == 255) {
        int c = 0;
        #pragma unroll
        for (int r = 0; r < 16; ++r) c += novL[r];
        nfcnt[blockIdx.x] = c;                     // non-atomic partial
    }
}

// ---------------------------------------------------------------- k_sym
// 2080 blocks x 256 thr. Tile t -> (a,b), a<=b; rows [a*128,+128) x cols
// [b*128,+128). Wave w owns rows [32w,+32); all waves share the 128 B-cols.
// D = Fb_row . Fc_col (unmasked, C-scaled on the col side). Per element:
// e = exp2(D); accR += e * novel[col]; colPartial += e * novel[row].
// Row-sums -> rowPart[row*64 + b]; col-sums -> rowPart[col*64 + a] (a!=b).
// First 8 diagonal tiles additionally reduce gpart->gOut and nfcnt->NnOut.
__global__ __launch_bounds__(256, 2) void k_sym(
        const unsigned short* __restrict__ Fb, const unsigned short* __restrict__ Fc,
        const int* __restrict__ nf,
        float* __restrict__ rowPart,
        const float* __restrict__ gpart, const int* __restrict__ nfcnt,
        float* __restrict__ gOut, int* __restrict__ NnOut) {
    __shared__ float colLds[4][128];
    __shared__ float gred[16][16];

    // decode linear tile -> (a,b), a<=b.  rs(a) = a*NT - a*(a-1)/2
    const int t = blockIdx.x;
    int a = (int)(((float)(2 * NT + 1)
                   - sqrtf((float)((2 * NT + 1) * (2 * NT + 1) - 8 * t))) * 0.5f);
    while ((a + 1) * NT - ((a + 1) * a) / 2 <= t) ++a;
    while (a * NT - (a * (a - 1)) / 2 > t) --a;
    const int b = a + (t - (a * NT - (a * (a - 1)) / 2));
    const int R0 = a * RT, C0 = b * RT;

    const int tid = threadIdx.x;
    const int wave = tid >> 6, lane = tid & 63;
    const int quad = lane >> 4, cq = lane & 15;

    // A fragments: rows R0 + wave*32 + mt*16 + cq, k = ks*32 + quad*8 .. +7
    short8 afr[2][4];
    #pragma unroll
    for (int mt = 0; mt < 2; ++mt)
        #pragma unroll
        for (int ks = 0; ks < 4; ++ks)
            afr[mt][ks] = *(const short8*)(Fb
                + (size_t)(R0 + wave * 32 + mt * 16 + cq) * K_DIM + ks * 32 + quad * 8);

    // row novelty masks for this lane's 8 D-rows (row = quad*4 + r within tile)
    float nmR[2][4];
    #pragma unroll
    for (int mt = 0; mt < 2; ++mt)
        #pragma unroll
        for (int r = 0; r < 4; ++r)
            nmR[mt][r] = (float)nf[R0 + wave * 32 + mt * 16 + quad * 4 + r];

    float accR[2][4];
    #pragma unroll
    for (int mt = 0; mt < 2; ++mt)
        #pragma unroll
        for (int r = 0; r < 4; ++r) accR[mt][r] = 0.f;

    // B fragments for ct=0, 1-deep rotation
    const unsigned short* bb = Fc + (size_t)(C0 + cq) * K_DIM + quad * 8;
    short8 b0 = *(const short8*)(bb);
    short8 b1 = *(const short8*)(bb + 32);
    short8 b2 = *(const short8*)(bb + 64);
    short8 b3 = *(const short8*)(bb + 96);
    float nmc = (float)nf[C0 + cq];

    #pragma unroll 1
    for (int ct = 0; ct < 8; ++ct) {
        const int nx = (ct < 7) ? ct + 1 : ct;   // last iter: reload same (unused)
        const unsigned short* nb = Fc + (size_t)(C0 + nx * 16 + cq) * K_DIM + quad * 8;
        short8 t0 = *(const short8*)(nb);
        short8 t1 = *(const short8*)(nb + 32);
        short8 t2 = *(const short8*)(nb + 64);
        short8 t3 = *(const short8*)(nb + 96);
        const float nmcn = (float)nf[C0 + nx * 16 + cq];

        floatx4 D0 = (floatx4){0.f, 0.f, 0.f, 0.f};
        floatx4 D1 = (floatx4){0.f, 0.f, 0.f, 0.f};
        D0 = __builtin_amdgcn_mfma_f32_16x16x32_bf16(afr[0][0], b0, D0, 0, 0, 0);
        D0 = __builtin_amdgcn_mfma_f32_16x16x32_bf16(afr[0][1], b1, D0, 0, 0, 0);
        D0 = __builtin_amdgcn_mfma_f32_16x16x32_bf16(afr[0][2], b2, D0, 0, 0, 0);
        D0 = __builtin_amdgcn_mfma_f32_16x16x32_bf16(afr[0][3], b3, D0, 0, 0, 0);
        D1 = __builtin_amdgcn_mfma_f32_16x16x32_bf16(afr[1][0], b0, D1, 0, 0, 0);
        D1 = __builtin_amdgcn_mfma_f32_16x16x32_bf16(afr[1][1], b1, D1, 0, 0, 0);
        D1 = __builtin_amdgcn_mfma_f32_16x16x32_bf16(afr[1][2], b2, D1, 0, 0, 0);
        D1 = __builtin_amdgcn_mfma_f32_16x16x32_bf16(afr[1][3], b3, D1, 0, 0, 0);

        float cp = 0.f;
        #pragma unroll
        for (int r = 0; r < 4; ++r) {
            const float e0 = EXP2(D0[r]);
            accR[0][r] += e0 * nmc;
            cp += e0 * nmR[0][r];
            const float e1 = EXP2(D1[r]);
            accR[1][r] += e1 * nmc;
            cp += e1 * nmR[1][r];
        }
        // column partial: sum over this wave's 32 rows (4 quads handled by shfl)
        cp += __shfl_xor(cp, 16);
        cp += __shfl_xor(cp, 32);
        if (quad == 0) colLds[wave][ct * 16 + cq] = cp;

        b0 = t0; b1 = t1; b2 = t2; b3 = t3; nmc = nmcn;
    }

    // row sums: reduce over the 16 cq lanes
    #pragma unroll
    for (int mt = 0; mt < 2; ++mt)
        #pragma unroll
        for (int r = 0; r < 4; ++r) {
            float e = accR[mt][r];
            e += __shfl_xor(e, 1); e += __shfl_xor(e, 2);
            e += __shfl_xor(e, 4); e += __shfl_xor(e, 8);
            accR[mt][r] = e;
        }
    if (cq == 0) {
        #pragma unroll
        for (int mt = 0; mt < 2; ++mt)
            #pragma unroll
            for (int r = 0; r < 4; ++r)
                rowPart[(size_t)(R0 + wave * 32 + mt * 16 + quad * 4 + r) * NSLOT + b]
                    = accR[mt][r];
    }

    __syncthreads();
    if (tid < 128 && a != b) {
        const float cs = colLds[0][tid] + colLds[1][tid] + colLds[2][tid] + colLds[3][tid];
        rowPart[(size_t)(C0 + tid) * NSLOT + a] = cs;
    }

    // -------- one-time g / Nn reduction on the first 8 diagonal tiles ------
    if (a == b && a < 8) {
        const int cl = (tid & 15) + 16 * a;
        const int rseg = tid >> 4;
        float s = 0.f;
        #pragma unroll 4
        for (int r = rseg; r < 512; r += 16) s += gpart[r * 128 + cl];
        gred[tid >> 4][tid & 15] = s;
        __syncthreads();
        if (tid < 16) {
            float tt = 0.f;
            #pragma unroll
            for (int k = 0; k < 16; ++k) tt += gred[k][tid];
            gOut[16 * a + tid] = tt;
        }
        if (a == 0 && tid >= 64 && tid < 128) {
            const int l = tid - 64;
            int cs = 0;
            #pragma unroll
            for (int r = 0; r < 8; ++r) cs += nfcnt[l + 64 * r];
            for (int off = 1; off < 64; off <<= 1) cs += __shfl_xor(cs, off);
            if (l == 0) *NnOut = cs;
        }
    }
}

// ---------------------------------------------------------------- k_final
// 512 blocks x 256 thr, 16 rows/block. Per row i: ep = sum of the 64 rowPart
// slots (= sum_{j novel} exp(S_ij), exact — no base-column correction);
// sZ = dot(Fb_i, g); dd = dot(Fb_i, Fc_i) = D_ii.
__global__ __launch_bounds__(256) void k_final(
        const int* __restrict__ nf,
        const float* __restrict__ rowPart,
        const float* __restrict__ Psum, const float* __restrict__ expPsum,
        const float* __restrict__ PLab,
        const unsigned short* __restrict__ Fb, const unsigned short* __restrict__ Fc,
        const float* __restrict__ gsrc, const int* __restrict__ NnPtr,
        float* __restrict__ out) {
    __shared__ float g[128];
    __shared__ float sh[16];
    __shared__ int shNn;
    const int tid = threadIdx.x;

    if (tid < 128) g[tid] = gsrc[tid];
    if (tid == 128) shNn = *NnPtr;
    __syncthreads();

    const int rp = tid >> 4, u = tid & 15;
    const int i = blockIdx.x * 16 + rp;
    uint4 qb = ((const uint4*)Fb)[(size_t)i * 16 + u];
    uint4 qz = ((const uint4*)Fc)[(size_t)i * 16 + u];
    float sZ = 0.f, dd = 0.f;
    {
        const float* gv = &g[u * 8];
        float fb[8], fz[8];
        fb[0]=lo_bf(qb.x); fb[1]=hi_bf(qb.x); fb[2]=lo_bf(qb.y); fb[3]=hi_bf(qb.y);
        fb[4]=lo_bf(qb.z); fb[5]=hi_bf(qb.z); fb[6]=lo_bf(qb.w); fb[7]=hi_bf(qb.w);
        fz[0]=lo_bf(qz.x); fz[1]=hi_bf(qz.x); fz[2]=lo_bf(qz.y); fz[3]=hi_bf(qz.y);
        fz[4]=lo_bf(qz.z); fz[5]=hi_bf(qz.z); fz[6]=lo_bf(qz.w); fz[7]=hi_bf(qz.w);
        #pragma unroll
        for (int e = 0; e < 8; ++e) { sZ += fb[e] * gv[e]; dd += fb[e] * fz[e]; }
    }
    // ep: 64 slots per row, float4 per lane
    float4 ev = ((const float4*)rowPart)[(size_t)i * 16 + u];
    float ep = ev.x + ev.y + ev.z + ev.w;
    for (int off = 1; off < 16; off <<= 1) {
        sZ += __shfl_xor(sZ, off);
        dd += __shfl_xor(dd, off);
        ep += __shfl_xor(ep, off);
    }

    if (u == 0) {
        const int Nn = shNn;
        float contrib;
        if (nf[i]) {
            const float cnt = (float)(Nn - 1);
            const float sumE = ep - EXP2(dd);                 // remove own diagonal
            const float denom = sumE + Psum[i];               // + RAW proto logit sum (faithful)
            const float sumS_raw = (sZ - dd) * INV_C;         // sum_{j novel, j!=i} dot_ij
            const float num = INV_T * sumS_raw - logf(denom) * cnt;
            const float sc = cnt > 0.f ? cnt : 1.f;
            contrib = -(num / sc);
        } else {
            contrib = -(PLab[i] - logf(ep + expPsum[i]));
        }
        sh[rp] = contrib;
    }
    __syncthreads();
    if (tid == 0) {
        float s = 0.f;
        #pragma unroll
        for (int r = 0; r < 16; ++r) s += sh[r];
        atomicAdd(out, s * (1.0f / (float)M_TOT));
    }
}

// ---------------------------------------------------------------- launch
extern "C" void kernel_launch(void* const* d_in, const int* in_sizes, int n_in,
                              void* d_out, int out_size, void* d_ws, size_t ws_size,
                              hipStream_t stream) {
    const float* feat    = (const float*)d_in[0];
    const int*   labels  = (const int*)d_in[1];
    const float* protos  = (const float*)d_in[2];
    const int*   plabels = (const int*)d_in[3];
    float* out = (float*)d_out;

    char* ws = (char*)d_ws;
    int*   nfcnt   = (int*)ws;                       // 512 ints
    int*   NnOut   = (int*)(ws + 4096);
    float* gOut    = (float*)(ws + 4608);            // 128 floats
    float* gpart   = (float*)(ws + 8192);            // 512 x 128 fp32 (256 KB)
    float* rowPart = (float*)(ws + 270336);          // 8192 x 64 fp32 (2 MB)
    float* Psum    = (float*)(ws + 2367488);
    float* expPsum = (float*)(ws + 2400256);
    float* PLab    = (float*)(ws + 2433024);
    int*   nf      = (int*)(ws + 2465792);
    unsigned short* Fb = (unsigned short*)(ws + 2498560);            // 2 MB, 16B aligned
    unsigned short* Fc = (unsigned short*)(ws + 2498560 + 2097152);  // 2 MB, 16B aligned

    k_proto2<<<M_TOT / 16, 256, 0, stream>>>(feat, labels, protos, plabels,
                                             Psum, expPsum, PLab, nf, nfcnt,
                                             Fb, Fc, gpart, out);
    k_sym<<<NTILE, 256, 0, stream>>>(Fb, Fc, nf, rowPart, gpart, nfcnt, gOut, NnOut);
    k_final<<<M_TOT / 16, 256, 0, stream>>>(nf, rowPart, Psum, expPsum, PLab,
                                            Fb, Fc, gOut, NnOut, out);
}

// Round 2
// 125.194 us; speedup vs baseline: 1.0605x; 1.0605x over previous
//
#include <hip/hip_runtime.h>
#include <stdint.h>

// SupConLossWithPrototype on MI355X.
// Round 13: attack latency-boundedness (all pipes <14% both prior rounds) and
// the hidden ~80us outside the big kernel.
//  - k_sym: 256x256 tiles split into two 128-row half-blocks -> 1056 blocks,
//    ~100 VGPR, ~4 blocks/CU resident (vs 2.7), 8 MFMAs/ct per wave, prologue
//    amortized 2x. Col-partials per half go to split slots (64 slots/row,
//    rowPartT zero-initialized in k_prep) -> atomic-free, deterministic.
//  - rowPartT transposed [slot][row]: round-1 scattered dword stores caused
//    write-allocate amplification (WRITE_SIZE 20MB for 2MB of data).
//  - k_prep (was k_proto2): proto GEMM switched from scalar VALU (~3000
//    instrs/thread) to MFMA (28 per block); nf computed directly from the
//    label test (never needed the GEMM).

#define M_TOT 8192
#define K_DIM 128
#define B_PRO 100
#define INV_T 5.0f                          // 1/TEMP
#define C_SCALE 7.2134752044448170f         // 5 * log2(e)
#define INV_C   0.1386294361119891f         // ln2/5
#define RT    256                           // k_sym tile side
#define NT    (M_TOT / RT)                  // 32 row/col groups
#define NTILE (NT * (NT + 1) / 2)           // 528 supra-diagonal tiles
#define NSLOT (2 * NT)                      // 64 partial slots per row (2 halves)
#define PB    112                           // padded proto rows (7 groups of 16)
#define PS    136                           // proto LDS stride (bf16 elems)
#define FS    136                           // feat LDS stride

#if __has_builtin(__builtin_amdgcn_exp2f)
#define EXP2(x) __builtin_amdgcn_exp2f(x)
#else
#define EXP2(x) __expf((x) * 0.6931471805599453f)
#endif

typedef __attribute__((ext_vector_type(8))) short  short8;   // 8 bf16 (MFMA A/B frag)
typedef __attribute__((ext_vector_type(4))) float  floatx4;  // MFMA C/D frag

__device__ __forceinline__ float bf2f(unsigned short u) {
    union { unsigned int i; float f; } v; v.i = ((unsigned int)u) << 16; return v.f;
}
__device__ __forceinline__ unsigned short f2bf(float x) {   // RNE
    union { float f; unsigned int i; } v; v.f = x;
    return (unsigned short)((v.i + 0x7fffu + ((v.i >> 16) & 1u)) >> 16);
}
__device__ __forceinline__ float lo_bf(unsigned int u) {
    union { unsigned int i; float f; } v; v.i = u << 16; return v.f;
}
__device__ __forceinline__ float hi_bf(unsigned int u) {
    union { unsigned int i; float f; } v; v.i = u & 0xffff0000u; return v.f;
}

// ---------------------------------------------------------------- k_prep
// 512 blocks x 256 thr; 16 feature rows per block.
//  - nf straight from labels x plabels (no GEMM dependency)
//  - Fb = bf16(f), Fc = bf16(C*f) (unmasked), gpart = block colsum of
//    novel-masked Fc, nfcnt = block novel count
//  - proto logits P via MFMA on a zero-padded 112-col proto tile; emits
//    Psum/expPsum/PLab
//  - zeroes its 4KB slice of rowPartT (k_sym only writes "live" slots)
__global__ __launch_bounds__(256) void k_prep(
        const float* __restrict__ feat, const int* __restrict__ labels,
        const float* __restrict__ protos, const int* __restrict__ plabels,
        float* __restrict__ Psum, float* __restrict__ expPsum,
        float* __restrict__ PLab, int* __restrict__ nf,
        int* __restrict__ nfcnt,
        unsigned short* __restrict__ Fb, unsigned short* __restrict__ Fc,
        float* __restrict__ gpart, float* __restrict__ rowPartT,
        float* __restrict__ out) {
    __shared__ unsigned short protoB[PB * PS];   // 30464 B
    __shared__ unsigned short featB[16 * FS];    // 4352 B
    __shared__ float zcol[16][128];              // 8192 B
    __shared__ float psW[4][16], esW[4][16], plW[4][16];
    __shared__ int labL[16];
    __shared__ int plabL[B_PRO];
    __shared__ int novL[16];

    const int tid = threadIdx.x;
    const int rowBase = blockIdx.x * 16;

    if (blockIdx.x == 0 && tid == 0) out[0] = 0.f;   // k_final accumulates later

    // zero this block's slice of rowPartT (64 slots x 8192 rows total = 2 MB)
    {
        floatx4 z4 = (floatx4){0.f, 0.f, 0.f, 0.f};
        ((floatx4*)rowPartT)[blockIdx.x * 256 + tid] = z4;
    }

    if (tid < B_PRO) plabL[tid] = plabels[tid];
    if (tid >= 128 && tid < 144) labL[tid - 128] = labels[rowBase + tid - 128];

    // stage protos -> bf16 LDS (3200 float4s strided over 256 threads)
    for (int idx = tid; idx < 3200; idx += 256) {
        const int pr = idx >> 5, sg = idx & 31;
        float4 v = ((const float4*)protos)[idx];
        *(ushort4*)&protoB[pr * PS + sg * 4] =
            make_ushort4(f2bf(v.x), f2bf(v.y), f2bf(v.z), f2bf(v.w));
    }
    for (int idx = tid; idx < 12 * 32; idx += 256) {   // zero-pad rows 100..111
        const int pr = B_PRO + (idx >> 5), sg = idx & 31;
        *(ushort4*)&protoB[pr * PS + sg * 4] = make_ushort4(0, 0, 0, 0);
    }

    // stage this thread's feat segment (row rp, cols pq*8..+7) -> LDS + Fb + Fc
    const int rp = tid >> 4, pq = tid & 15;
    ushort4 s0, s1;
    {
        const float* src = feat + (size_t)(rowBase + rp) * K_DIM + pq * 8;
        float4 fa  = ((const float4*)src)[0];
        float4 fb4 = ((const float4*)src)[1];
        ushort4 o0 = make_ushort4(f2bf(fa.x), f2bf(fa.y), f2bf(fa.z), f2bf(fa.w));
        ushort4 o1 = make_ushort4(f2bf(fb4.x), f2bf(fb4.y), f2bf(fb4.z), f2bf(fb4.w));
        *(ushort4*)&featB[rp * FS + pq * 8]     = o0;
        *(ushort4*)&featB[rp * FS + pq * 8 + 4] = o1;
        unsigned short* fbd = Fb + (size_t)(rowBase + rp) * K_DIM + pq * 8;
        *(ushort4*)&fbd[0] = o0;
        *(ushort4*)&fbd[4] = o1;
        s0 = make_ushort4(f2bf(fa.x*C_SCALE), f2bf(fa.y*C_SCALE),
                          f2bf(fa.z*C_SCALE), f2bf(fa.w*C_SCALE));
        s1 = make_ushort4(f2bf(fb4.x*C_SCALE), f2bf(fb4.y*C_SCALE),
                          f2bf(fb4.z*C_SCALE), f2bf(fb4.w*C_SCALE));
        unsigned short* fcd = Fc + (size_t)(rowBase + rp) * K_DIM + pq * 8;
        *(ushort4*)&fcd[0] = s0;
        *(ushort4*)&fcd[4] = s1;
    }
    __syncthreads();

    // novelty from the label test: nf[i] = !(labels[i] in plabels)
    const int lbl = labL[rp];
    float flg = 0.f;
    #pragma unroll
    for (int j = 0; j < 7; ++j) {
        const int jj = pq + 16 * j;
        if (jj < B_PRO && plabL[jj] == lbl) flg = 1.f;
    }
    for (int off = 1; off < 16; off <<= 1) flg += __shfl_xor(flg, off);
    const bool nov = (flg == 0.f);
    {
        const float m = nov ? 1.f : 0.f;
        float* zc = &zcol[rp][pq * 8];
        zc[0] = m*bf2f(s0.x); zc[1] = m*bf2f(s0.y); zc[2] = m*bf2f(s0.z); zc[3] = m*bf2f(s0.w);
        zc[4] = m*bf2f(s1.x); zc[5] = m*bf2f(s1.y); zc[6] = m*bf2f(s1.z); zc[7] = m*bf2f(s1.w);
        if (pq == 0) {
            const int nv = nov ? 1 : 0;
            nf[rowBase + rp] = nv;
            novL[rp] = nv;
        }
    }

    // proto GEMM via MFMA: wave w handles col-group w (and w+4 if w<3)
    const int wv = tid >> 6, lane = tid & 63, quad = lane >> 4, cq = lane & 15;
    short8 af[4];
    #pragma unroll
    for (int ks = 0; ks < 4; ++ks)
        af[ks] = *(const short8*)&featB[cq * FS + ks * 32 + quad * 8];

    float ps_[4] = {0.f, 0.f, 0.f, 0.f};
    float es_[4] = {0.f, 0.f, 0.f, 0.f};
    float pl_[4] = {0.f, 0.f, 0.f, 0.f};

    #pragma unroll
    for (int gi = 0; gi < 2; ++gi) {
        const int g = wv + 4 * gi;
        if (gi == 1 && wv >= 3) break;     // groups 0..6 only
        short8 bf[4];
        #pragma unroll
        for (int ks = 0; ks < 4; ++ks)
            bf[ks] = *(const short8*)&protoB[(g * 16 + cq) * PS + ks * 32 + quad * 8];
        floatx4 D = (floatx4){0.f, 0.f, 0.f, 0.f};
        D = __builtin_amdgcn_mfma_f32_16x16x32_bf16(af[0], bf[0], D, 0, 0, 0);
        D = __builtin_amdgcn_mfma_f32_16x16x32_bf16(af[1], bf[1], D, 0, 0, 0);
        D = __builtin_amdgcn_mfma_f32_16x16x32_bf16(af[2], bf[2], D, 0, 0, 0);
        D = __builtin_amdgcn_mfma_f32_16x16x32_bf16(af[3], bf[3], D, 0, 0, 0);
        #pragma unroll
        for (int r = 0; r < 4; ++r) {
            const int bcol = g * 16 + cq;
            if (bcol < B_PRO) {
                const float Pv = D[r] * INV_T;
                ps_[r] += Pv;
                es_[r] += __expf(Pv);
                if (bcol == labL[quad * 4 + r]) pl_[r] += Pv;
            }
        }
    }
    #pragma unroll
    for (int r = 0; r < 4; ++r) {
        for (int off = 1; off < 16; off <<= 1) {
            ps_[r] += __shfl_xor(ps_[r], off);
            es_[r] += __shfl_xor(es_[r], off);
            pl_[r] += __shfl_xor(pl_[r], off);
        }
        if (cq == 0) {
            psW[wv][quad * 4 + r] = ps_[r];
            esW[wv][quad * 4 + r] = es_[r];
            plW[wv][quad * 4 + r] = pl_[r];
        }
    }
    __syncthreads();

    if (tid < 16) {
        const int i = rowBase + tid;
        Psum[i]    = psW[0][tid] + psW[1][tid] + psW[2][tid] + psW[3][tid];
        expPsum[i] = esW[0][tid] + esW[1][tid] + esW[2][tid] + esW[3][tid];
        PLab[i]    = plW[0][tid] + plW[1][tid] + plW[2][tid] + plW[3][tid];
    }
    if (tid < 128) {
        float s = 0.f;
        #pragma unroll
        for (int r = 0; r < 16; ++r) s += zcol[r][tid];
        gpart[blockIdx.x * 128 + tid] = s;         // non-atomic partial
    } else if (tid == 255) {
        int c = 0;
        #pragma unroll
        for (int r = 0; r < 16; ++r) c += novL[r];
        nfcnt[blockIdx.x] = c;                     // non-atomic partial
    }
}

// ---------------------------------------------------------------- k_sym
// 1056 blocks x 256 thr: tile t=blockIdx>>1 -> (a,b) a<=b, half h=blockIdx&1.
// Rows [a*256 + h*128, +128) x cols [b*256, +256). Wave w owns 32 rows; all
// waves share the 256 B-cols (16 cts of 16). Per element e = exp2(D):
// accR += e*novel[col]; colPartial += e*novel[row].
// Row-sums -> rowPartT[(2b+h)][row]; col-sums -> rowPartT[(2a+h)][col] (a!=b).
// Unwritten slots stay zero (k_prep memset). First 8 diagonal h==0 blocks
// also reduce gpart->gOut and nfcnt->NnOut.
__global__ __launch_bounds__(256, 2) void k_sym(
        const unsigned short* __restrict__ Fb, const unsigned short* __restrict__ Fc,
        const int* __restrict__ nf,
        float* __restrict__ rowPartT,
        const float* __restrict__ gpart, const int* __restrict__ nfcnt,
        float* __restrict__ gOut, int* __restrict__ NnOut) {
    __shared__ float colLds[4][256];
    __shared__ float gred[16][16];

    // decode linear tile -> (a,b), a<=b.  rs(a) = a*NT - a*(a-1)/2
    const int t = blockIdx.x >> 1, h = blockIdx.x & 1;
    int a = (int)(((float)(2 * NT + 1)
                   - sqrtf((float)((2 * NT + 1) * (2 * NT + 1) - 8 * t))) * 0.5f);
    while ((a + 1) * NT - ((a + 1) * a) / 2 <= t) ++a;
    while (a * NT - (a * (a - 1)) / 2 > t) --a;
    const int b = a + (t - (a * NT - (a * (a - 1)) / 2));
    const int R0 = a * RT + h * 128, C0 = b * RT;

    const int tid = threadIdx.x;
    const int wv = tid >> 6, lane = tid & 63;
    const int quad = lane >> 4, cq = lane & 15;

    // A fragments: rows R0 + wv*32 + mt*16 + cq, k = ks*32 + quad*8 .. +7
    short8 afr[2][4];
    #pragma unroll
    for (int mt = 0; mt < 2; ++mt)
        #pragma unroll
        for (int ks = 0; ks < 4; ++ks)
            afr[mt][ks] = *(const short8*)(Fb
                + (size_t)(R0 + wv * 32 + mt * 16 + cq) * K_DIM + ks * 32 + quad * 8);

    // row novelty masks for this lane's 8 D-rows
    float nmR[2][4];
    #pragma unroll
    for (int mt = 0; mt < 2; ++mt)
        #pragma unroll
        for (int r = 0; r < 4; ++r)
            nmR[mt][r] = (float)nf[R0 + wv * 32 + mt * 16 + quad * 4 + r];

    float accR[2][4];
    #pragma unroll
    for (int mt = 0; mt < 2; ++mt)
        #pragma unroll
        for (int r = 0; r < 4; ++r) accR[mt][r] = 0.f;

    // B fragments for ct=0, 1-deep rotation
    const unsigned short* bb = Fc + (size_t)(C0 + cq) * K_DIM + quad * 8;
    short8 b0 = *(const short8*)(bb);
    short8 b1 = *(const short8*)(bb + 32);
    short8 b2 = *(const short8*)(bb + 64);
    short8 b3 = *(const short8*)(bb + 96);
    float nmc = (float)nf[C0 + cq];

    #pragma unroll 1
    for (int ct = 0; ct < 16; ++ct) {
        const int nx = (ct < 15) ? ct + 1 : ct;   // last iter: reload same (unused)
        const unsigned short* nb = Fc + (size_t)(C0 + nx * 16 + cq) * K_DIM + quad * 8;
        short8 t0 = *(const short8*)(nb);
        short8 t1 = *(const short8*)(nb + 32);
        short8 t2 = *(const short8*)(nb + 64);
        short8 t3 = *(const short8*)(nb + 96);
        const float nmcn = (float)nf[C0 + nx * 16 + cq];

        floatx4 D0 = (floatx4){0.f, 0.f, 0.f, 0.f};
        floatx4 D1 = (floatx4){0.f, 0.f, 0.f, 0.f};
        D0 = __builtin_amdgcn_mfma_f32_16x16x32_bf16(afr[0][0], b0, D0, 0, 0, 0);
        D0 = __builtin_amdgcn_mfma_f32_16x16x32_bf16(afr[0][1], b1, D0, 0, 0, 0);
        D0 = __builtin_amdgcn_mfma_f32_16x16x32_bf16(afr[0][2], b2, D0, 0, 0, 0);
        D0 = __builtin_amdgcn_mfma_f32_16x16x32_bf16(afr[0][3], b3, D0, 0, 0, 0);
        D1 = __builtin_amdgcn_mfma_f32_16x16x32_bf16(afr[1][0], b0, D1, 0, 0, 0);
        D1 = __builtin_amdgcn_mfma_f32_16x16x32_bf16(afr[1][1], b1, D1, 0, 0, 0);
        D1 = __builtin_amdgcn_mfma_f32_16x16x32_bf16(afr[1][2], b2, D1, 0, 0, 0);
        D1 = __builtin_amdgcn_mfma_f32_16x16x32_bf16(afr[1][3], b3, D1, 0, 0, 0);

        float cp = 0.f;
        #pragma unroll
        for (int r = 0; r < 4; ++r) {
            const float e0 = EXP2(D0[r]);
            accR[0][r] += e0 * nmc;
            cp += e0 * nmR[0][r];
            const float e1 = EXP2(D1[r]);
            accR[1][r] += e1 * nmc;
            cp += e1 * nmR[1][r];
        }
        cp += __shfl_xor(cp, 16);
        cp += __shfl_xor(cp, 32);
        if (quad == 0) colLds[wv][ct * 16 + cq] = cp;

        b0 = t0; b1 = t1; b2 = t2; b3 = t3; nmc = nmcn;
    }

    // row sums: reduce over the 16 cq lanes, write slot 2b+h
    #pragma unroll
    for (int mt = 0; mt < 2; ++mt)
        #pragma unroll
        for (int r = 0; r < 4; ++r) {
            float e = accR[mt][r];
            e += __shfl_xor(e, 1); e += __shfl_xor(e, 2);
            e += __shfl_xor(e, 4); e += __shfl_xor(e, 8);
            accR[mt][r] = e;
        }
    if (cq == 0) {
        #pragma unroll
        for (int mt = 0; mt < 2; ++mt)
            #pragma unroll
            for (int r = 0; r < 4; ++r)
                rowPartT[(size_t)(2 * b + h) * M_TOT
                         + R0 + wv * 32 + mt * 16 + quad * 4 + r] = accR[mt][r];
    }

    __syncthreads();
    if (a != b) {
        const float cs = colLds[0][tid] + colLds[1][tid] + colLds[2][tid] + colLds[3][tid];
        rowPartT[(size_t)(2 * a + h) * M_TOT + C0 + tid] = cs;
    }

    // -------- one-time g / Nn reduction on the first 8 diagonal h==0 blocks --
    if (a == b && h == 0 && a < 8) {
        const int cl = (tid & 15) + 16 * a;
        const int rseg = tid >> 4;
        float s = 0.f;
        #pragma unroll 4
        for (int r = rseg; r < 512; r += 16) s += gpart[r * 128 + cl];
        gred[tid >> 4][tid & 15] = s;
        __syncthreads();
        if (tid < 16) {
            float tt = 0.f;
            #pragma unroll
            for (int k = 0; k < 16; ++k) tt += gred[k][tid];
            gOut[16 * a + tid] = tt;
        }
        if (a == 0 && tid >= 64 && tid < 128) {
            const int l = tid - 64;
            int cs = 0;
            #pragma unroll
            for (int r = 0; r < 8; ++r) cs += nfcnt[l + 64 * r];
            for (int off = 1; off < 64; off <<= 1) cs += __shfl_xor(cs, off);
            if (l == 0) *NnOut = cs;
        }
    }
}

// ---------------------------------------------------------------- k_final
// 512 blocks x 256 thr, 16 rows/block. Per row i: ep = sum of the 64 rowPartT
// slots (= sum_{j novel} exp(S_ij), exact); sZ = dot(Fb_i, g);
// dd = dot(Fb_i, Fc_i) = D_ii.
__global__ __launch_bounds__(256) void k_final(
        const int* __restrict__ nf,
        const float* __restrict__ rowPartT,
        const float* __restrict__ Psum, const float* __restrict__ expPsum,
        const float* __restrict__ PLab,
        const unsigned short* __restrict__ Fb, const unsigned short* __restrict__ Fc,
        const float* __restrict__ gsrc, const int* __restrict__ NnPtr,
        float* __restrict__ out) {
    __shared__ float g[128];
    __shared__ float sh[16];
    __shared__ int shNn;
    const int tid = threadIdx.x;

    if (tid < 128) g[tid] = gsrc[tid];
    if (tid == 128) shNn = *NnPtr;
    __syncthreads();

    const int rp = tid >> 4, u = tid & 15;
    const int i = blockIdx.x * 16 + rp;
    uint4 qb = ((const uint4*)Fb)[(size_t)i * 16 + u];
    uint4 qz = ((const uint4*)Fc)[(size_t)i * 16 + u];
    float sZ = 0.f, dd = 0.f;
    {
        const float* gv = &g[u * 8];
        float fb[8], fz[8];
        fb[0]=lo_bf(qb.x); fb[1]=hi_bf(qb.x); fb[2]=lo_bf(qb.y); fb[3]=hi_bf(qb.y);
        fb[4]=lo_bf(qb.z); fb[5]=hi_bf(qb.z); fb[6]=lo_bf(qb.w); fb[7]=hi_bf(qb.w);
        fz[0]=lo_bf(qz.x); fz[1]=hi_bf(qz.x); fz[2]=lo_bf(qz.y); fz[3]=hi_bf(qz.y);
        fz[4]=lo_bf(qz.z); fz[5]=hi_bf(qz.z); fz[6]=lo_bf(qz.w); fz[7]=hi_bf(qz.w);
        #pragma unroll
        for (int e = 0; e < 8; ++e) { sZ += fb[e] * gv[e]; dd += fb[e] * fz[e]; }
    }
    // ep: 64 transposed slots per row, 4 per lane
    float ep = rowPartT[(size_t)u * M_TOT + i]
             + rowPartT[(size_t)(u + 16) * M_TOT + i]
             + rowPartT[(size_t)(u + 32) * M_TOT + i]
             + rowPartT[(size_t)(u + 48) * M_TOT + i];
    for (int off = 1; off < 16; off <<= 1) {
        sZ += __shfl_xor(sZ, off);
        dd += __shfl_xor(dd, off);
        ep += __shfl_xor(ep, off);
    }

    if (u == 0) {
        const int Nn = shNn;
        float contrib;
        if (nf[i]) {
            const float cnt = (float)(Nn - 1);
            const float sumE = ep - EXP2(dd);                 // remove own diagonal
            const float denom = sumE + Psum[i];               // + RAW proto logit sum (faithful)
            const float sumS_raw = (sZ - dd) * INV_C;         // sum_{j novel, j!=i} dot_ij
            const float num = INV_T * sumS_raw - logf(denom) * cnt;
            const float sc = cnt > 0.f ? cnt : 1.f;
            contrib = -(num / sc);
        } else {
            contrib = -(PLab[i] - logf(ep + expPsum[i]));
        }
        sh[rp] = contrib;
    }
    __syncthreads();
    if (tid == 0) {
        float s = 0.f;
        #pragma unroll
        for (int r = 0; r < 16; ++r) s += sh[r];
        atomicAdd(out, s * (1.0f / (float)M_TOT));
    }
}

// ---------------------------------------------------------------- launch
extern "C" void kernel_launch(void* const* d_in, const int* in_sizes, int n_in,
                              void* d_out, int out_size, void* d_ws, size_t ws_size,
                              hipStream_t stream) {
    const float* feat    = (const float*)d_in[0];
    const int*   labels  = (const int*)d_in[1];
    const float* protos  = (const float*)d_in[2];
    const int*   plabels = (const int*)d_in[3];
    float* out = (float*)d_out;

    char* ws = (char*)d_ws;
    int*   nfcnt    = (int*)ws;                      // 512 ints
    int*   NnOut    = (int*)(ws + 4096);
    float* gOut     = (float*)(ws + 4608);           // 128 floats
    float* gpart    = (float*)(ws + 8192);           // 512 x 128 fp32 (256 KB)
    float* rowPartT = (float*)(ws + 270336);         // 64 x 8192 fp32 (2 MB)
    float* Psum     = (float*)(ws + 2367488);
    float* expPsum  = (float*)(ws + 2400256);
    float* PLab     = (float*)(ws + 2433024);
    int*   nf       = (int*)(ws + 2465792);
    unsigned short* Fb = (unsigned short*)(ws + 2498560);            // 2 MB, 16B aligned
    unsigned short* Fc = (unsigned short*)(ws + 2498560 + 2097152);  // 2 MB, 16B aligned

    k_prep<<<M_TOT / 16, 256, 0, stream>>>(feat, labels, protos, plabels,
                                           Psum, expPsum, PLab, nf, nfcnt,
                                           Fb, Fc, gpart, rowPartT, out);
    k_sym<<<2 * NTILE, 256, 0, stream>>>(Fb, Fc, nf, rowPartT, gpart, nfcnt,
                                         gOut, NnOut);
    k_final<<<M_TOT / 16, 256, 0, stream>>>(nf, rowPartT, Psum, expPsum, PLab,
                                            Fb, Fc, gOut, NnOut, out);
}